// Round 6
// baseline (156.734 us; speedup 1.0000x reference)
//
#include <hip/hip_runtime.h>
#include <math.h>

#define BSZ 512
#define DD 2048
#define KK 128
#define PP 5
#define NCOL (KK * PP)   // 640
#define OUTW (DD + KK)   // 2176
#define LOG2E 1.4426950408889634f

#define KSPLIT 8
#define GM 64            // m rows per block (lane dim)
#define GN 64            // n cols per block (4 waves x 16)
#define GK (DD / KSPLIT) // 256 k-depth per split
#define GBK 32           // k chunk staged in LDS
#define QSPLIT 8         // pairwise b2 chunks

// ws layout (floats): scale[640] | actv[512*640] | part[8*512*640]  (~11.8 MB)
#define WS_SCALE 0
#define WS_ACTV (WS_SCALE + NCOL)
#define WS_PART (WS_ACTV + BSZ * NCOL)

// ---------------------------------------------------------------------------
// Kernel 1: fused prep. Block-uniform branch on blockIdx.x:
//   [0,1024)    : copy x -> out[:, :D] (float4)
//   [1024,1280) : out[:, D:] = bias - 1   (pairwise atomically accumulates)
//   [1280,1320) : norm of 16 theta cols/block -> scale[col], NO atomics
// ---------------------------------------------------------------------------
__global__ __launch_bounds__(256) void prep_kernel(const float* __restrict__ x,
                                                   const float* __restrict__ theta,
                                                   const float* __restrict__ lws,
                                                   const float* __restrict__ bias,
                                                   float* __restrict__ out,
                                                   float* __restrict__ scale) {
    const int bid = blockIdx.x;
    const int tid = threadIdx.x;
    if (bid < 1024) {
        int i = bid * 256 + tid;            // 512 rows * 512 float4
        int r = i >> 9;
        int c = i & 511;
        float4 v = *(const float4*)&x[(size_t)r * DD + c * 4];
        *(float4*)&out[(size_t)r * OUTW + c * 4] = v;
    } else if (bid < 1280) {
        int i = (bid - 1024) * 256 + tid;   // 0..65535
        int b = i >> 7;
        int k = i & 127;
        out[(size_t)b * OUTW + DD + k] = bias[k] - 1.0f;
    } else {
        // 40 blocks x 16 cols: col = col0 + (t&15); 16 k-segments per col
        __shared__ float snorm[16][17];
        const int col0 = (bid - 1280) * 16;
        const int co  = tid & 15;
        const int seg = tid >> 4;           // 0..15
        const float* p = theta + (size_t)seg * 128 * NCOL + col0 + co;
        float s = 0.f;
        for (int j = 0; j < 128; ++j) {
            float v = p[(size_t)j * NCOL];
            s += v * v;
        }
        snorm[seg][co] = s;
        __syncthreads();
        if (tid < 16) {
            float t = 0.f;
#pragma unroll
            for (int g = 0; g < 16; ++g) t += snorm[g][tid];
            const int col = col0 + tid;
            scale[col] = __builtin_amdgcn_exp2f(lws[col] * LOG2E) *
                         __builtin_amdgcn_rsqf(t) * LOG2E;
        }
    }
}

// ---------------------------------------------------------------------------
// Kernel 2: split-K GEMM, scalar-B form, software-pipelined staging.
// Wave: lane = m row, 16 n-cols per wave. A (x) in LDS (ds_read_b32, 2-way =
// free). B (theta) via wave-uniform SGPR addresses -> s_load (scalar pipe).
// KSPLIT=8 -> 640 blocks (10 waves/CU). Plain float4 stores, no atomics.
// ---------------------------------------------------------------------------
__global__ __launch_bounds__(256) void gemm_kernel(const float* __restrict__ x,
                                                   const float* __restrict__ theta,
                                                   float* __restrict__ part) {
    __shared__ float xT[GBK][GM];   // [kk][m], 8 KiB

    const int t    = threadIdx.x;
    const int lane = t & 63;
    const int wave = t >> 6;                 // 0..3
    const int m    = blockIdx.y * GM + lane;
    const int kz   = blockIdx.z * GK;
    const int nw = __builtin_amdgcn_readfirstlane(blockIdx.x * GN + wave * 16);

    const float* xrow = x + (size_t)m * DD;

    float acc[16] = {};

    float4 v0 = *(const float4*)&xrow[kz + wave * 8];
    float4 v1 = *(const float4*)&xrow[kz + wave * 8 + 4];

    for (int kc = kz; kc < kz + GK; kc += GBK) {
        __syncthreads();   // previous chunk's LDS reads complete
        xT[wave * 8 + 0][lane] = v0.x;
        xT[wave * 8 + 1][lane] = v0.y;
        xT[wave * 8 + 2][lane] = v0.z;
        xT[wave * 8 + 3][lane] = v0.w;
        xT[wave * 8 + 4][lane] = v1.x;
        xT[wave * 8 + 5][lane] = v1.y;
        xT[wave * 8 + 6][lane] = v1.z;
        xT[wave * 8 + 7][lane] = v1.w;
        __syncthreads();

        if (kc + GBK < kz + GK) {            // next chunk's loads in flight
            v0 = *(const float4*)&xrow[kc + GBK + wave * 8];
            v1 = *(const float4*)&xrow[kc + GBK + wave * 8 + 4];
        }

        const float* th = &theta[(size_t)kc * NCOL + nw];
#pragma unroll 4
        for (int kk = 0; kk < GBK; ++kk) {
            const float a = xT[kk][lane];
#pragma unroll
            for (int j = 0; j < 16; ++j)
                acc[j] += a * th[(size_t)kk * NCOL + j];   // wave-uniform -> s_load
        }
    }

    float* dst = part + (size_t)blockIdx.z * (BSZ * NCOL) + (size_t)m * NCOL + nw;
    *(float4*)&dst[0]  = make_float4(acc[0],  acc[1],  acc[2],  acc[3]);
    *(float4*)&dst[4]  = make_float4(acc[4],  acc[5],  acc[6],  acc[7]);
    *(float4*)&dst[8]  = make_float4(acc[8],  acc[9],  acc[10], acc[11]);
    *(float4*)&dst[12] = make_float4(acc[12], acc[13], acc[14], acc[15]);
}

// ---------------------------------------------------------------------------
// Kernel 3: reduce 8 split-K partials, multiply precomputed scale.
// actv is pre-scaled by log2(e): pairwise uses exp2 with free neg-modifier.
// ---------------------------------------------------------------------------
__global__ __launch_bounds__(256) void reduce_kernel(const float* __restrict__ part,
                                                     const float* __restrict__ scale,
                                                     float* __restrict__ actv) {
    int i   = blockIdx.x * 256 + threadIdx.x;   // 0..327679
    int col = i % NCOL;
    float s = 0.f;
#pragma unroll
    for (int q = 0; q < KSPLIT; ++q)
        s += part[(size_t)q * (BSZ * NCOL) + i];
    actv[i] = s * scale[col];
}

// ---------------------------------------------------------------------------
// Kernel 4: pairwise L1 -> exp2 -> partial rowsum over 64-wide b2 chunk.
// Block = 128 threads, 4 b-rows each; per b2: 2 DS insts feed 4 rows of VALU
// -> VALU-bound. grid (k=128, q=8). Epilogue fused: atomicAdd partials into
// out[:, D:] (pre-initialized to bias-1 by prep). 0.5M atomics total.
// ---------------------------------------------------------------------------
__global__ __launch_bounds__(128) void pairwise_kernel(const float* __restrict__ actv,
                                                       float* __restrict__ out) {
    const int k   = blockIdx.x;    // 0..127
    const int q   = blockIdx.y;    // 0..7
    const int tid = threadIdx.x;   // 0..127

    __shared__ float sB[64][8];    // 2 KiB, rows 32B-aligned

    for (int i = tid; i < 64 * PP; i += 128) {   // 320 entries
        int r = i / PP;
        int p = i - r * PP;
        sB[r][p] = actv[(size_t)(q * 64 + r) * NCOL + k * PP + p];
    }

    float a[4][PP];
#pragma unroll
    for (int r = 0; r < 4; ++r) {
        const float* ap = &actv[(size_t)(tid + r * 128) * NCOL + k * PP];
#pragma unroll
        for (int p = 0; p < PP; ++p) a[r][p] = ap[p];
    }
    __syncthreads();

    float acc[4] = {0.f, 0.f, 0.f, 0.f};
#pragma unroll 2
    for (int j = 0; j < 64; ++j) {
        const float4 v  = *(const float4*)&sB[j][0];
        const float  v4 = sB[j][4];
#pragma unroll
        for (int r = 0; r < 4; ++r) {
            float s = fabsf(a[r][0] - v.x) + fabsf(a[r][1] - v.y) +
                      fabsf(a[r][2] - v.z) + fabsf(a[r][3] - v.w) +
                      fabsf(a[r][4] - v4);
            acc[r] += __builtin_amdgcn_exp2f(-s);   // actv pre-scaled by log2e
        }
    }

#pragma unroll
    for (int r = 0; r < 4; ++r)
        atomicAdd(&out[(size_t)(tid + r * 128) * OUTW + DD + k], acc[r]);
}

// ---------------------------------------------------------------------------
extern "C" void kernel_launch(void* const* d_in, const int* in_sizes, int n_in,
                              void* d_out, int out_size, void* d_ws, size_t ws_size,
                              hipStream_t stream) {
    const float* x     = (const float*)d_in[0];   // [512, 2048]
    const float* theta = (const float*)d_in[1];   // [2048, 128, 5]
    const float* lws   = (const float*)d_in[2];   // [128, 5]
    const float* bias  = (const float*)d_in[3];   // [128]
    float* out = (float*)d_out;                   // [512, 2176]

    float* ws    = (float*)d_ws;
    float* scale = ws + WS_SCALE;
    float* actv  = ws + WS_ACTV;
    float* part  = ws + WS_PART;

    prep_kernel<<<1320, 256, 0, stream>>>(x, theta, lws, bias, out, scale);
    gemm_kernel<<<dim3(NCOL / GN, BSZ / GM, KSPLIT), 256, 0, stream>>>(x, theta, part);
    reduce_kernel<<<(BSZ * NCOL) / 256, 256, 0, stream>>>(part, scale, actv);
    pairwise_kernel<<<dim3(KK, QSPLIT), 128, 0, stream>>>(actv, out);
}

// Round 7
// 125.875 us; speedup vs baseline: 1.2452x; 1.2452x over previous
//
#include <hip/hip_runtime.h>
#include <math.h>

#define BSZ 512
#define DD 2048
#define KK 128
#define PP 5
#define NCOL (KK * PP)   // 640
#define OUTW (DD + KK)   // 2176
#define LOG2E 1.4426950408889634f

#define KSPLIT 8
#define GM 64            // m rows per block (lane dim)
#define GN 64            // n cols per block (4 waves x 16)
#define GK (DD / KSPLIT) // 256 k-depth per split
#define GBK 32           // k chunk staged in LDS
#define QSPLIT 8         // pairwise b2 chunks

// ws layout (floats): scale[640] | actv[512*640] | f_part[8*128*512] | part[8*512*640]
#define WS_SCALE 0
#define WS_ACTV (WS_SCALE + NCOL)
#define WS_FPART (WS_ACTV + BSZ * NCOL)
#define WS_PART (WS_FPART + QSPLIT * KK * BSZ)

// ---------------------------------------------------------------------------
// Kernel 1: fused prep. Block-uniform branch:
//   [0,1024)    : copy x -> out[:, :D] (float4)
//   [1024,1064) : norm of 16 theta cols/block -> scale[col], NO atomics
// ---------------------------------------------------------------------------
__global__ __launch_bounds__(256) void prep_kernel(const float* __restrict__ x,
                                                   const float* __restrict__ theta,
                                                   const float* __restrict__ lws,
                                                   float* __restrict__ out,
                                                   float* __restrict__ scale) {
    const int bid = blockIdx.x;
    const int tid = threadIdx.x;
    if (bid < 1024) {
        int i = bid * 256 + tid;            // 512 rows * 512 float4
        int r = i >> 9;
        int c = i & 511;
        float4 v = *(const float4*)&x[(size_t)r * DD + c * 4];
        *(float4*)&out[(size_t)r * OUTW + c * 4] = v;
    } else {
        // 40 blocks x 16 cols: col = col0 + (t&15); 16 k-segments per col
        __shared__ float snorm[16][17];
        const int col0 = (bid - 1024) * 16;
        const int co  = tid & 15;
        const int seg = tid >> 4;           // 0..15
        const float* p = theta + (size_t)seg * 128 * NCOL + col0 + co;
        float s = 0.f;
        for (int j = 0; j < 128; ++j) {
            float v = p[(size_t)j * NCOL];
            s += v * v;
        }
        snorm[seg][co] = s;
        __syncthreads();
        if (tid < 16) {
            float t = 0.f;
#pragma unroll
            for (int g = 0; g < 16; ++g) t += snorm[g][tid];
            const int col = col0 + tid;
            scale[col] = __builtin_amdgcn_exp2f(lws[col] * LOG2E) *
                         __builtin_amdgcn_rsqf(t) * LOG2E;
        }
    }
}

// ---------------------------------------------------------------------------
// Kernel 2: split-K GEMM, scalar-B form, software-pipelined staging.
// Wave: lane = m row, 16 n-cols per wave. A (x) in LDS (ds_read_b32, 2-way =
// free). B (theta) via wave-uniform SGPR addresses -> s_load (scalar pipe).
// KSPLIT=8 -> 640 blocks (10 waves/CU). Plain float4 stores, no atomics.
// ---------------------------------------------------------------------------
__global__ __launch_bounds__(256) void gemm_kernel(const float* __restrict__ x,
                                                   const float* __restrict__ theta,
                                                   float* __restrict__ part) {
    __shared__ float xT[GBK][GM];   // [kk][m], 8 KiB

    const int t    = threadIdx.x;
    const int lane = t & 63;
    const int wave = t >> 6;                 // 0..3
    const int m    = blockIdx.y * GM + lane;
    const int kz   = blockIdx.z * GK;
    const int nw = __builtin_amdgcn_readfirstlane(blockIdx.x * GN + wave * 16);

    const float* xrow = x + (size_t)m * DD;

    float acc[16] = {};

    float4 v0 = *(const float4*)&xrow[kz + wave * 8];
    float4 v1 = *(const float4*)&xrow[kz + wave * 8 + 4];

    for (int kc = kz; kc < kz + GK; kc += GBK) {
        __syncthreads();   // previous chunk's LDS reads complete
        xT[wave * 8 + 0][lane] = v0.x;
        xT[wave * 8 + 1][lane] = v0.y;
        xT[wave * 8 + 2][lane] = v0.z;
        xT[wave * 8 + 3][lane] = v0.w;
        xT[wave * 8 + 4][lane] = v1.x;
        xT[wave * 8 + 5][lane] = v1.y;
        xT[wave * 8 + 6][lane] = v1.z;
        xT[wave * 8 + 7][lane] = v1.w;
        __syncthreads();

        if (kc + GBK < kz + GK) {            // next chunk's loads in flight
            v0 = *(const float4*)&xrow[kc + GBK + wave * 8];
            v1 = *(const float4*)&xrow[kc + GBK + wave * 8 + 4];
        }

        const float* th = &theta[(size_t)kc * NCOL + nw];
#pragma unroll 4
        for (int kk = 0; kk < GBK; ++kk) {
            const float a = xT[kk][lane];
#pragma unroll
            for (int j = 0; j < 16; ++j)
                acc[j] += a * th[(size_t)kk * NCOL + j];   // wave-uniform -> s_load
        }
    }

    float* dst = part + (size_t)blockIdx.z * (BSZ * NCOL) + (size_t)m * NCOL + nw;
    *(float4*)&dst[0]  = make_float4(acc[0],  acc[1],  acc[2],  acc[3]);
    *(float4*)&dst[4]  = make_float4(acc[4],  acc[5],  acc[6],  acc[7]);
    *(float4*)&dst[8]  = make_float4(acc[8],  acc[9],  acc[10], acc[11]);
    *(float4*)&dst[12] = make_float4(acc[12], acc[13], acc[14], acc[15]);
}

// ---------------------------------------------------------------------------
// Kernel 3: reduce 8 split-K partials, multiply precomputed scale.
// actv is pre-scaled by log2(e): pairwise uses exp2 with free neg-modifier.
// ---------------------------------------------------------------------------
__global__ __launch_bounds__(256) void reduce_kernel(const float* __restrict__ part,
                                                     const float* __restrict__ scale,
                                                     float* __restrict__ actv) {
    int i   = blockIdx.x * 256 + threadIdx.x;   // 0..327679
    int col = i % NCOL;
    float s = 0.f;
#pragma unroll
    for (int q = 0; q < KSPLIT; ++q)
        s += part[(size_t)q * (BSZ * NCOL) + i];
    actv[i] = s * scale[col];
}

// ---------------------------------------------------------------------------
// Kernel 4: pairwise L1 -> exp2 -> partial rowsum over 64-wide b2 chunk.
// Block = 128 threads, 4 b-rows each; per b2: 2 DS insts feed 4 rows of VALU
// -> VALU-bound. grid (k=128, q=8). COALESCED plain stores to f_part
// (R5's scatter atomicAdds to out cost ~40 us: cross-XCD coherence-point
// serialization, 128 RMWs per cacheline. NO bulk atomics, ever.)
// ---------------------------------------------------------------------------
__global__ __launch_bounds__(128) void pairwise_kernel(const float* __restrict__ actv,
                                                       float* __restrict__ f_part) {
    const int k   = blockIdx.x;    // 0..127
    const int q   = blockIdx.y;    // 0..7
    const int tid = threadIdx.x;   // 0..127

    __shared__ float sB[64][8];    // 2 KiB, rows 32B-aligned

    for (int i = tid; i < 64 * PP; i += 128) {   // 320 entries
        int r = i / PP;
        int p = i - r * PP;
        sB[r][p] = actv[(size_t)(q * 64 + r) * NCOL + k * PP + p];
    }

    float a[4][PP];
#pragma unroll
    for (int r = 0; r < 4; ++r) {
        const float* ap = &actv[(size_t)(tid + r * 128) * NCOL + k * PP];
#pragma unroll
        for (int p = 0; p < PP; ++p) a[r][p] = ap[p];
    }
    __syncthreads();

    float acc[4] = {0.f, 0.f, 0.f, 0.f};
#pragma unroll 2
    for (int j = 0; j < 64; ++j) {
        const float4 v  = *(const float4*)&sB[j][0];
        const float  v4 = sB[j][4];
#pragma unroll
        for (int r = 0; r < 4; ++r) {
            float s = fabsf(a[r][0] - v.x) + fabsf(a[r][1] - v.y) +
                      fabsf(a[r][2] - v.z) + fabsf(a[r][3] - v.w) +
                      fabsf(a[r][4] - v4);
            acc[r] += __builtin_amdgcn_exp2f(-s);   // actv pre-scaled by log2e
        }
    }

    float* fp = f_part + ((size_t)q * KK + k) * BSZ;
#pragma unroll
    for (int r = 0; r < 4; ++r)
        fp[tid + r * 128] = acc[r];      // coalesced plain stores
}

// ---------------------------------------------------------------------------
// Kernel 5: finalize — reduce f_part over q, add bias-1, write out[:, D:].
// ---------------------------------------------------------------------------
__global__ __launch_bounds__(256) void finalize_kernel(const float* __restrict__ f_part,
                                                       const float* __restrict__ bias,
                                                       float* __restrict__ out) {
    int i = blockIdx.x * 256 + threadIdx.x;   // 0..65535
    int k = i >> 9;          // 0..127
    int b = i & 511;         // lanes vary b -> coalesced f_part reads
    float s = 0.f;
#pragma unroll
    for (int q = 0; q < QSPLIT; ++q)
        s += f_part[((size_t)q * KK + k) * BSZ + b];
    out[(size_t)b * OUTW + DD + k] = s - 1.0f + bias[k];
}

// ---------------------------------------------------------------------------
extern "C" void kernel_launch(void* const* d_in, const int* in_sizes, int n_in,
                              void* d_out, int out_size, void* d_ws, size_t ws_size,
                              hipStream_t stream) {
    const float* x     = (const float*)d_in[0];   // [512, 2048]
    const float* theta = (const float*)d_in[1];   // [2048, 128, 5]
    const float* lws   = (const float*)d_in[2];   // [128, 5]
    const float* bias  = (const float*)d_in[3];   // [128]
    float* out = (float*)d_out;                   // [512, 2176]

    float* ws     = (float*)d_ws;
    float* scale  = ws + WS_SCALE;
    float* actv   = ws + WS_ACTV;
    float* f_part = ws + WS_FPART;
    float* part   = ws + WS_PART;

    prep_kernel<<<1064, 256, 0, stream>>>(x, theta, lws, out, scale);
    gemm_kernel<<<dim3(NCOL / GN, BSZ / GM, KSPLIT), 256, 0, stream>>>(x, theta, part);
    reduce_kernel<<<(BSZ * NCOL) / 256, 256, 0, stream>>>(part, scale, actv);
    pairwise_kernel<<<dim3(KK, QSPLIT), 128, 0, stream>>>(actv, f_part);
    finalize_kernel<<<(BSZ * KK) / 256, 256, 0, stream>>>(f_part, bias, out);
}

// Round 8
// 125.501 us; speedup vs baseline: 1.2489x; 1.0030x over previous
//
#include <hip/hip_runtime.h>
#include <math.h>

#define BSZ 512
#define DD 2048
#define KK 128
#define PP 5
#define NCOL (KK * PP)   // 640
#define OUTW (DD + KK)   // 2176
#define LOG2E 1.4426950408889634f

#define KSPLIT 16
#define GM 64            // m rows per block (lane dim)
#define GN 32            // n cols per block (4 waves x 8)
#define GK (DD / KSPLIT) // 128 k-depth per split
#define GBK 32           // k chunk staged in LDS
#define QSPLIT 8         // pairwise b2 chunks

// ws layout (floats): scale[640] | actv[512*640] | f_part[8*128*512] | part[16*512*640]
#define WS_SCALE 0
#define WS_ACTV (WS_SCALE + NCOL)
#define WS_FPART (WS_ACTV + BSZ * NCOL)
#define WS_PART (WS_FPART + QSPLIT * KK * BSZ)

// ---------------------------------------------------------------------------
// Kernel 1: fused prep. Block-uniform branch:
//   [0,1024)    : copy x -> out[:, :D] (float4)
//   [1024,1064) : norm of 16 theta cols/block -> scale[col], NO atomics
// ---------------------------------------------------------------------------
__global__ __launch_bounds__(256) void prep_kernel(const float* __restrict__ x,
                                                   const float* __restrict__ theta,
                                                   const float* __restrict__ lws,
                                                   float* __restrict__ out,
                                                   float* __restrict__ scale) {
    const int bid = blockIdx.x;
    const int tid = threadIdx.x;
    if (bid < 1024) {
        int i = bid * 256 + tid;            // 512 rows * 512 float4
        int r = i >> 9;
        int c = i & 511;
        float4 v = *(const float4*)&x[(size_t)r * DD + c * 4];
        *(float4*)&out[(size_t)r * OUTW + c * 4] = v;
    } else {
        // 40 blocks x 16 cols: col = col0 + (t&15); 16 k-segments per col
        __shared__ float snorm[16][17];
        const int col0 = (bid - 1024) * 16;
        const int co  = tid & 15;
        const int seg = tid >> 4;           // 0..15
        const float* p = theta + (size_t)seg * 128 * NCOL + col0 + co;
        float s = 0.f;
        for (int j = 0; j < 128; ++j) {
            float v = p[(size_t)j * NCOL];
            s += v * v;
        }
        snorm[seg][co] = s;
        __syncthreads();
        if (tid < 16) {
            float t = 0.f;
#pragma unroll
            for (int g = 0; g < 16; ++g) t += snorm[g][tid];
            const int col = col0 + tid;
            scale[col] = __builtin_amdgcn_exp2f(lws[col] * LOG2E) *
                         __builtin_amdgcn_rsqf(t) * LOG2E;
        }
    }
}

// ---------------------------------------------------------------------------
// Kernel 2: split-K GEMM, scalar-B form. n-tile 32, KSPLIT 16 ->
// grid 20x8x16 = 2560 blocks = 10 waves/SIMD demanded (HW-capped 8: full).
// Wave: lane = m row, 8 n-cols (acc[8], low VGPR). A (x) staged in LDS,
// B (theta) via wave-uniform SGPR address -> s_load. Plain stores, no atomics.
// ---------------------------------------------------------------------------
__global__ __launch_bounds__(256) void gemm_kernel(const float* __restrict__ x,
                                                   const float* __restrict__ theta,
                                                   float* __restrict__ part) {
    __shared__ float xT[GBK][GM];   // [kk][m], 8 KiB

    const int t    = threadIdx.x;
    const int lane = t & 63;
    const int wave = t >> 6;                 // 0..3
    const int m    = blockIdx.y * GM + lane;
    const int kz   = blockIdx.z * GK;
    const int nw = __builtin_amdgcn_readfirstlane(blockIdx.x * GN + wave * 8);

    const float* xrow = x + (size_t)m * DD;

    float acc[8] = {};

    float4 v0 = *(const float4*)&xrow[kz + wave * 8];
    float4 v1 = *(const float4*)&xrow[kz + wave * 8 + 4];

    for (int kc = kz; kc < kz + GK; kc += GBK) {
        __syncthreads();   // previous chunk's LDS reads complete
        xT[wave * 8 + 0][lane] = v0.x;
        xT[wave * 8 + 1][lane] = v0.y;
        xT[wave * 8 + 2][lane] = v0.z;
        xT[wave * 8 + 3][lane] = v0.w;
        xT[wave * 8 + 4][lane] = v1.x;
        xT[wave * 8 + 5][lane] = v1.y;
        xT[wave * 8 + 6][lane] = v1.z;
        xT[wave * 8 + 7][lane] = v1.w;
        __syncthreads();

        if (kc + GBK < kz + GK) {            // next chunk's loads in flight
            v0 = *(const float4*)&xrow[kc + GBK + wave * 8];
            v1 = *(const float4*)&xrow[kc + GBK + wave * 8 + 4];
        }

        const float* th = &theta[(size_t)kc * NCOL + nw];
#pragma unroll 4
        for (int kk = 0; kk < GBK; ++kk) {
            const float a = xT[kk][lane];
#pragma unroll
            for (int j = 0; j < 8; ++j)
                acc[j] += a * th[(size_t)kk * NCOL + j];   // wave-uniform -> s_load
        }
    }

    float* dst = part + (size_t)blockIdx.z * (BSZ * NCOL) + (size_t)m * NCOL + nw;
    *(float4*)&dst[0] = make_float4(acc[0], acc[1], acc[2], acc[3]);
    *(float4*)&dst[4] = make_float4(acc[4], acc[5], acc[6], acc[7]);
}

// ---------------------------------------------------------------------------
// Kernel 3: reduce 16 split-K partials, multiply precomputed scale.
// actv is pre-scaled by log2(e): pairwise uses exp2 with free neg-modifier.
// ---------------------------------------------------------------------------
__global__ __launch_bounds__(256) void reduce_kernel(const float* __restrict__ part,
                                                     const float* __restrict__ scale,
                                                     float* __restrict__ actv) {
    int i   = blockIdx.x * 256 + threadIdx.x;   // 0..327679
    int col = i % NCOL;
    float s = 0.f;
#pragma unroll
    for (int q = 0; q < KSPLIT; ++q)
        s += part[(size_t)q * (BSZ * NCOL) + i];
    actv[i] = s * scale[col];
}

// ---------------------------------------------------------------------------
// Kernel 4: pairwise L1 -> exp2 -> partial rowsum over 64-wide b2 chunk.
// Block = 128 threads, 4 b-rows each; per b2: 2 DS insts feed 4 rows of VALU
// -> VALU-bound. grid (k=128, q=8). COALESCED plain stores to f_part
// (scatter atomics to out cost ~40 us in R5 — never again).
// ---------------------------------------------------------------------------
__global__ __launch_bounds__(128) void pairwise_kernel(const float* __restrict__ actv,
                                                       float* __restrict__ f_part) {
    const int k   = blockIdx.x;    // 0..127
    const int q   = blockIdx.y;    // 0..7
    const int tid = threadIdx.x;   // 0..127

    __shared__ float sB[64][8];    // 2 KiB, rows 32B-aligned

    for (int i = tid; i < 64 * PP; i += 128) {   // 320 entries
        int r = i / PP;
        int p = i - r * PP;
        sB[r][p] = actv[(size_t)(q * 64 + r) * NCOL + k * PP + p];
    }

    float a[4][PP];
#pragma unroll
    for (int r = 0; r < 4; ++r) {
        const float* ap = &actv[(size_t)(tid + r * 128) * NCOL + k * PP];
#pragma unroll
        for (int p = 0; p < PP; ++p) a[r][p] = ap[p];
    }
    __syncthreads();

    float acc[4] = {0.f, 0.f, 0.f, 0.f};
#pragma unroll 2
    for (int j = 0; j < 64; ++j) {
        const float4 v  = *(const float4*)&sB[j][0];
        const float  v4 = sB[j][4];
#pragma unroll
        for (int r = 0; r < 4; ++r) {
            float s = fabsf(a[r][0] - v.x) + fabsf(a[r][1] - v.y) +
                      fabsf(a[r][2] - v.z) + fabsf(a[r][3] - v.w) +
                      fabsf(a[r][4] - v4);
            acc[r] += __builtin_amdgcn_exp2f(-s);   // actv pre-scaled by log2e
        }
    }

    float* fp = f_part + ((size_t)q * KK + k) * BSZ;
#pragma unroll
    for (int r = 0; r < 4; ++r)
        fp[tid + r * 128] = acc[r];      // coalesced plain stores
}

// ---------------------------------------------------------------------------
// Kernel 5: finalize — reduce f_part over q, add bias-1, write out[:, D:].
// ---------------------------------------------------------------------------
__global__ __launch_bounds__(256) void finalize_kernel(const float* __restrict__ f_part,
                                                       const float* __restrict__ bias,
                                                       float* __restrict__ out) {
    int i = blockIdx.x * 256 + threadIdx.x;   // 0..65535
    int k = i >> 9;          // 0..127
    int b = i & 511;         // lanes vary b -> coalesced f_part reads
    float s = 0.f;
#pragma unroll
    for (int q = 0; q < QSPLIT; ++q)
        s += f_part[((size_t)q * KK + k) * BSZ + b];
    out[(size_t)b * OUTW + DD + k] = s - 1.0f + bias[k];
}

// ---------------------------------------------------------------------------
extern "C" void kernel_launch(void* const* d_in, const int* in_sizes, int n_in,
                              void* d_out, int out_size, void* d_ws, size_t ws_size,
                              hipStream_t stream) {
    const float* x     = (const float*)d_in[0];   // [512, 2048]
    const float* theta = (const float*)d_in[1];   // [2048, 128, 5]
    const float* lws   = (const float*)d_in[2];   // [128, 5]
    const float* bias  = (const float*)d_in[3];   // [128]
    float* out = (float*)d_out;                   // [512, 2176]

    float* ws     = (float*)d_ws;
    float* scale  = ws + WS_SCALE;
    float* actv   = ws + WS_ACTV;
    float* f_part = ws + WS_FPART;
    float* part   = ws + WS_PART;

    prep_kernel<<<1064, 256, 0, stream>>>(x, theta, lws, out, scale);
    gemm_kernel<<<dim3(NCOL / GN, BSZ / GM, KSPLIT), 256, 0, stream>>>(x, theta, part);
    reduce_kernel<<<(BSZ * NCOL) / 256, 256, 0, stream>>>(part, scale, actv);
    pairwise_kernel<<<dim3(KK, QSPLIT), 128, 0, stream>>>(actv, f_part);
    finalize_kernel<<<(BSZ * KK) / 256, 256, 0, stream>>>(f_part, bias, out);
}